// Round 3
// baseline (887.182 us; speedup 1.0000x reference)
//
#include <hip/hip_runtime.h>

// SS2D_Mamba fused, bf16-MFMA GEMM + fp32 sigmoid/scan.
// Per block = one sequence n=b*H+h (768 blocks, 256 thr = 4 waves).
// Wave v computes param type v (o in [v*256, v*256+256)).
// Per quarter (24 w): A = bf16 x-tile [32m][256k] in LDS (XOR-swizzled);
// B = weight streamed from L2 in pre-packed fragment order; acc[2][16] f4.
// Sigmoid in regs; params exchanged via 48KB LDS f4 tiles (two 12-w halves)
// to the per-channel scan (thread t scans channel t, fp32 x from regs).

#define H_DIM 96
#define W_DIM 96
#define C_DIM 256
#define QW    24
#define NQ    4

typedef float f4  __attribute__((ext_vector_type(4)));
typedef short s4v __attribute__((ext_vector_type(4)));
typedef short s8v __attribute__((ext_vector_type(8)));

__device__ __forceinline__ unsigned short f2bf(float f) {
  union { float f; unsigned u; } v; v.f = f;           // RNE bf16
  unsigned r = v.u + 0x7FFFu + ((v.u >> 16) & 1u);
  return (unsigned short)(r >> 16);
}

__device__ __forceinline__ float sigf(float z) {
  return __builtin_amdgcn_rcpf(1.0f + __builtin_amdgcn_exp2f(z * -1.44269504088896340736f));
}

// weight[1024][256] f32 -> bf16 B-fragments.
// idx = (tile*8 + s)*64 + lane ; reg j: n = tile*16+(lane&15),
// k = s*32 + ((lane>>4)&3)*4 + (j&3) + ((j>>2)<<4).  (Any k-bijection works
// as long as the A-side uses the same map — MFMA pairs same (group,reg).)
__global__ void pack_w(const float* __restrict__ w, s8v* __restrict__ wp)
{
  const int idx  = blockIdx.x * 256 + threadIdx.x;   // 0..32767
  const int lane = idx & 63;
  const int s    = (idx >> 6) & 7;
  const int tile = idx >> 9;
  const int n    = tile * 16 + (lane & 15);
  const int kb   = s * 32 + ((lane >> 4) & 3) * 4;
  const float* wr = w + (size_t)n * C_DIM;
  s8v v;
#pragma unroll
  for (int j = 0; j < 8; ++j) {
    const int k = kb + (j & 3) + ((j >> 2) << 4);
    v[j] = (short)f2bf(wr[k]);
  }
  wp[idx] = v;
}

__global__ __launch_bounds__(256, 2) void ss2d_mfma(
    const float* __restrict__ x, const s8v* __restrict__ wp,
    const float* __restrict__ bias, float* __restrict__ y)
{
  __shared__ char Ald[32 * 512];      // A: [32 m][256 k] bf16, kbyte ^= (m&7)<<3
  __shared__ f4   plds[12 * 256];     // params half-tile [w'][c] = {a,b,c,d}

  const int tid  = threadIdx.x;
  const int lane = tid & 63;
  const int wv   = tid >> 6;          // wave id == param type
  const int nb   = blockIdx.x;
  const int b    = nb / H_DIM;
  const int h    = nb - b * H_DIM;

  const size_t rowoff = ((size_t)(b * C_DIM + tid) * H_DIM + h) * W_DIM;
  const float* xrow = x + rowoff;     // channel tid's 96 floats of (b,h)
  float*       yrow = y + rowoff;

  // zero A pad rows 24..31 (k = tid), so pad MFMA rows stay finite
#pragma unroll
  for (int m = 24; m < 32; ++m)
    *(short*)(Ald + m * 512 + ((tid * 2) ^ ((m & 7) << 3))) = 0;

  // bias for my 16 n-tiles: col n = wv*256 + nt*16 + (lane&15)
  float bcol[16];
#pragma unroll
  for (int nt = 0; nt < 16; ++nt)
    bcol[nt] = bias[wv * 256 + nt * 16 + (lane & 15)];

  f4 xq[6], xq2[6];
#pragma unroll
  for (int i = 0; i < 6; ++i) xq[i] = *(const f4*)(xrow + i * 4);

  float hstate = 0.0f;
  const int m0   = lane & 15;
  const int g    = lane >> 4;
  const int rb0  = m0 * 512;
  const int xorm = (m0 & 7) << 3;

  for (int q = 0; q < NQ; ++q) {
    // ---- stage A: A[m][k=tid] = bf16(x), m = 0..23 (writes conflict-free) --
#pragma unroll
    for (int m = 0; m < QW; ++m)
      *(short*)(Ald + m * 512 + ((tid * 2) ^ ((m & 7) << 3))) =
          (short)f2bf(xq[m >> 2][m & 3]);
    if (q < NQ - 1) {
#pragma unroll
      for (int i = 0; i < 6; ++i)
        xq2[i] = *(const f4*)(xrow + (q + 1) * QW + i * 4);
    }
    __syncthreads();                  // A visible to all waves

    // ---- GEMM: D[m=w][n=o], 2 M-tiles x 16 N-tiles, K=256 ----
    f4 acc0[16], acc1[16];
#pragma unroll
    for (int nt = 0; nt < 16; ++nt) {
      const f4 iv = { bcol[nt], bcol[nt], bcol[nt], bcol[nt] };
      acc0[nt] = iv; acc1[nt] = iv;
    }
    for (int s = 0; s < 8; ++s) {
      const int kb = s * 64 + (g << 3);
      const int x0 = kb ^ xorm;
      const int x1 = (kb + 32) ^ xorm;
      const s4v a0l = *(const s4v*)(Ald + rb0 + x0);
      const s4v a0h = *(const s4v*)(Ald + rb0 + x1);
      const s4v a1l = *(const s4v*)(Ald + 8192 + rb0 + x0);
      const s4v a1h = *(const s4v*)(Ald + 8192 + rb0 + x1);
      const s8v a0 = __builtin_shufflevector(a0l, a0h, 0,1,2,3,4,5,6,7);
      const s8v a1 = __builtin_shufflevector(a1l, a1h, 0,1,2,3,4,5,6,7);
      const s8v* wrow = wp + ((size_t)(wv * 16) * 8 + s) * 64 + lane;
#pragma unroll
      for (int nt = 0; nt < 16; ++nt) {
        const s8v bf = wrow[(size_t)nt * 8 * 64];   // coalesced b128, L2-hot
        acc0[nt] = __builtin_amdgcn_mfma_f32_16x16x32_bf16(a0, bf, acc0[nt], 0, 0, 0);
        acc1[nt] = __builtin_amdgcn_mfma_f32_16x16x32_bf16(a1, bf, acc1[nt], 0, 0, 0);
      }
    }

    // ---- sigmoid on all fragments (pad rows harmless, never stored) ----
#pragma unroll
    for (int nt = 0; nt < 16; ++nt)
#pragma unroll
      for (int j = 0; j < 4; ++j) {
        acc0[nt][j] = sigf(acc0[nt][j]);
        acc1[nt][j] = sigf(acc1[nt][j]);
      }

    // ---- exchange + scan, two halves of 12 w ----
    // D layout: row w = mt*16 + 4g + j, col o = wv*256 + nt*16 + m0 (m89)
#pragma unroll
    for (int half = 0; half < 2; ++half) {
      __syncthreads();                // plds free (prev half consumed)
#pragma unroll
      for (int nt = 0; nt < 16; ++nt) {
        const int c = nt * 16 + m0;
        float* base = (float*)&plds[0] + (size_t)c * 4 + wv;
#pragma unroll
        for (int j = 0; j < 4; ++j) {
          const int w0 = 4 * g + j;          // mt0 rows: w 0..15
          if (half == 0) {
            if (w0 < 12) base[(size_t)w0 * 1024] = acc0[nt][j];
          } else {
            if (w0 >= 12) base[(size_t)(w0 - 12) * 1024] = acc0[nt][j];
            const int w1 = 16 + 4 * g + j;   // mt1 rows: w 16..23 valid
            if (w1 < 24) base[(size_t)(w1 - 12) * 1024] = acc1[nt][j];
          }
        }
      }
      __syncthreads();                // plds ready
      f4 yo[3];
#pragma unroll
      for (int wq = 0; wq < 12; ++wq) {
        const f4 p = plds[wq * 256 + tid];   // b128, conflict-free
        const int wg = half * 12 + wq;
        const float xv = xq[wg >> 2][wg & 3];    // fp32 x from regs
        hstate = p[0] * hstate + p[1] * xv;
        yo[wq >> 2][wq & 3] = p[2] * hstate + p[3] * xv;
      }
#pragma unroll
      for (int i = 0; i < 3; ++i)
        *(f4*)(yrow + q * QW + half * 12 + i * 4) = yo[i];
    }
#pragma unroll
    for (int i = 0; i < 6; ++i) xq[i] = xq2[i];
  }
}

extern "C" void kernel_launch(void* const* d_in, const int* in_sizes, int n_in,
                              void* d_out, int out_size, void* d_ws, size_t ws_size,
                              hipStream_t stream)
{
  const float* x    = (const float*)d_in[0];
  const float* w    = (const float*)d_in[1];
  const float* bias = (const float*)d_in[2];
  float* y = (float*)d_out;

  s8v* wp = (s8v*)d_ws;   // 64*8*64 frags * 16B = 512 KB

  hipLaunchKernelGGL(pack_w, dim3(128), dim3(256), 0, stream, w, wp);
  hipLaunchKernelGGL(ss2d_mfma, dim3(8 * H_DIM), dim3(256), 0, stream,
                     x, wp, bias, y);
}